// Round 7
// baseline (127.080 us; speedup 1.0000x reference)
//
#include <hip/hip_runtime.h>

namespace {

constexpr int B = 4;
constexpr int N = 8192;          // power of two (N = 1<<13)
constexpr int E = 24576;
constexpr int BN = B * N;
constexpr int CHUNK = 128;       // staged points per block (2 KB packed)
constexpr int SUB = 64;          // argmin subblock granularity (matches rescan wave)
constexpr int RT = 16;           // rows per thread (register-tiled)

typedef float f32x2 __attribute__((ext_vector_type(2)));

// Monotonic float <-> uint mapping (total order matches float compare)
__device__ __forceinline__ unsigned fkey(float f) {
  unsigned b = __float_as_uint(f);
  return b ^ ((b & 0x80000000u) ? 0xFFFFFFFFu : 0x80000000u);
}
__device__ __forceinline__ float funkey(unsigned k) {
  unsigned b = k ^ ((k & 0x80000000u) ? 0x80000000u : 0xFFFFFFFFu);
  return __uint_as_float(b);
}
// 3-input min in one instruction (T17)
__device__ __forceinline__ float min3f(float a, float b, float c) {
  float d;
  asm("v_min3_f32 %0, %1, %2, %3" : "=v"(d) : "v"(a), "v"(b), "v"(c));
  return d;
}
// packed 2xf32 fma: D.lo = a.lo*b.lo + c.lo; D.hi = a.hi*b.hi + c.hi
__device__ __forceinline__ f32x2 pk_fma(f32x2 a, f32x2 b, f32x2 c) {
  f32x2 d;
  asm("v_pk_fma_f32 %0, %1, %2, %3" : "=v"(d) : "v"(a), "v"(b), "v"(c));
  return d;
}

// sums layout (floats): [0]=s1, [1]=s2, [2]=cos sum, [3..14]=nsq[b][d], [15..26]=vsq[b][d]

// A[i] = (-2*p, |p|^2) etc; A2/G2 = pair-packed: for pair p (points 2p,2p+1):
//   float4[2p]   = (x_{2p}, x_{2p+1}, y_{2p}, y_{2p+1})
//   float4[2p+1] = (z_{2p}, z_{2p+1}, w_{2p}, w_{2p+1})
__global__ __launch_bounds__(256) void prep_kernel(const float* __restrict__ preds,
                                                   const float* __restrict__ gts,
                                                   float4* __restrict__ A,
                                                   float4* __restrict__ G,
                                                   float* __restrict__ A2f,
                                                   float* __restrict__ G2f,
                                                   unsigned long long* __restrict__ m2,
                                                   unsigned* __restrict__ m1,
                                                   float* __restrict__ sums) {
  int i = blockIdx.x * 256 + threadIdx.x;
  float px = preds[3*i], py = preds[3*i+1], pz = preds[3*i+2];
  float gx = gts[3*i],   gy = gts[3*i+1],  gz = gts[3*i+2];
  float ax = -2.f*px, ay = -2.f*py, az = -2.f*pz, aw = px*px + py*py + pz*pz;
  float bx = -2.f*gx, by = -2.f*gy, bz = -2.f*gz, bw = gx*gx + gy*gy + gz*gz;
  A[i] = make_float4(ax, ay, az, aw);
  G[i] = make_float4(bx, by, bz, bw);
  int p8 = (i >> 1) * 8, l = i & 1;
  A2f[p8 + 0 + l] = ax; A2f[p8 + 2 + l] = ay; A2f[p8 + 4 + l] = az; A2f[p8 + 6 + l] = aw;
  G2f[p8 + 0 + l] = bx; G2f[p8 + 2 + l] = by; G2f[p8 + 4 + l] = bz; G2f[p8 + 6 + l] = bw;
  m2[i] = ~0ULL;
  m1[i] = 0xFFFFFFFFu;
  if (i < 32) sums[i] = 0.f;
}

// Fused min pass: blockIdx.z = b + 4*which.
//   which=0: rows = gts, staged = preds(packed A2) -> m2 (min over m + subblock)
//   which=1: rows = preds, staged = gts(packed G2) -> m1 (min over n)
// Each thread owns RT=16 rows; per 2 staged points per row: 3 v_pk_fma_f32 + 1 v_min3.
// Packed fma chain order == rescan's scalar fmaf chain (bitwise identical).
// CHUNK=128 -> 1024 blocks; (256,3) -> 3 waves/SIMD for latency hiding.
__global__ __launch_bounds__(256, 3) void pass_fused(const float4* __restrict__ A,
                                                     const float4* __restrict__ G,
                                                     const float4* __restrict__ A2,
                                                     const float4* __restrict__ G2,
                                                     unsigned long long* __restrict__ m2,
                                                     unsigned* __restrict__ m1) {
  __shared__ float4 sh[CHUNK];   // CHUNK float4s = CHUNK/2 packed pair-records
  const int which = blockIdx.z >> 2, b = blockIdx.z & 3;
  const float4* __restrict__ R  = which ? A  : G;
  const float4* __restrict__ S2 = which ? G2 : A2;
  const int rt = blockIdx.y, ck = blockIdx.x;
  const int tid = threadIdx.x;
  const int base = ck * CHUNK;                 // in points
  if (tid < CHUNK) sh[tid] = S2[b * N + base + tid];
  __syncthreads();
  f32x2 x2[RT], y2[RT], z2[RT];
  float best[RT];
  int sbb[RT];
#pragma unroll
  for (int i = 0; i < RT; ++i) {
    float4 r = R[b * N + rt * (256 * RT) + i * 256 + tid];
    float xx = -0.5f * r.x, yy = -0.5f * r.y, zz = -0.5f * r.z;
    x2[i] = f32x2{xx, xx}; y2[i] = f32x2{yy, yy}; z2[i] = f32x2{zz, zz};
    best[i] = 3.4e38f; sbb[i] = 0;
  }
  for (int sb = 0; sb < CHUNK; sb += SUB) {
    float a[RT];
#pragma unroll
    for (int i = 0; i < RT; ++i) a[i] = 3.4e38f;
    const float4* shp = &sh[sb];
#pragma unroll 4
    for (int jr = 0; jr < SUB / 2; ++jr) {     // 32 pair-records of 2 points
      float4 qa = shp[2*jr], qb = shp[2*jr + 1];
      f32x2 qx = f32x2{qa.x, qa.y}, qy = f32x2{qa.z, qa.w};
      f32x2 qz = f32x2{qb.x, qb.y}, qw = f32x2{qb.z, qb.w};
#pragma unroll
      for (int i = 0; i < RT; ++i) {
        f32x2 t = pk_fma(z2[i], qz, qw);
        t = pk_fma(y2[i], qy, t);
        t = pk_fma(x2[i], qx, t);
        a[i] = min3f(a[i], t.x, t.y);
      }
    }
#pragma unroll
    for (int i = 0; i < RT; ++i)
      if (a[i] < best[i]) { best[i] = a[i]; sbb[i] = base + sb; }  // strict <: earliest subblock wins ties
  }
#pragma unroll
  for (int i = 0; i < RT; ++i) {
    const int gi = b * N + rt * (256 * RT) + i * 256 + tid;
    float d = R[gi].w + best[i];               // re-read w (L2-resident) to save 16 VGPRs
    if (which == 0) {
      atomicMin(&m2[gi], ((unsigned long long)fkey(d) << 32) | (unsigned)sbb[i]);
    } else {
      atomicMin(&m1[gi], fkey(d));
    }
  }
}

__device__ __forceinline__ float block_sum(float v, float* ws) {
#pragma unroll
  for (int o = 32; o; o >>= 1) v += __shfl_down(v, o, 64);
  __syncthreads();
  if ((threadIdx.x & 63) == 0) ws[threadIdx.x >> 6] = v;
  __syncthreads();
  return ws[0] + ws[1] + ws[2] + ws[3];
}

// Merged: blocks [0, BN/4): rescan (one wave per row, re-scan winning 64-pt
// subblock with bitwise-identical scalar fmaf chain, ballot -> first match);
// blocks [BN/4, BN/4 + BN/256): reduce m1/m2 keys into sums.
constexpr int RESCAN_BLOCKS = BN / 4;
__global__ __launch_bounds__(256) void post_kernel(const float4* __restrict__ G,
                                                   const float4* __restrict__ A,
                                                   const unsigned long long* __restrict__ m2,
                                                   const unsigned* __restrict__ m1,
                                                   unsigned* __restrict__ nidx,
                                                   float* __restrict__ sums) {
  __shared__ float ws[4];
  if (blockIdx.x < RESCAN_BLOCKS) {
    const int row  = (blockIdx.x * 256 + threadIdx.x) >> 6;   // 4 rows per block
    const int lane = threadIdx.x & 63;
    const int b = row >> 13;          // / N
    const int n = row & (N - 1);
    const int gi = b * N + n;
    unsigned long long p = m2[gi];
    const unsigned kd = (unsigned)(p >> 32);
    const int base = (int)(unsigned)p;
    float4 r = G[gi];
    const float x = -0.5f*r.x, y = -0.5f*r.y, z = -0.5f*r.z, w = r.w;
    float4 q = A[b * N + base + lane];
    float v = fmaf(x, q.x, fmaf(y, q.y, fmaf(z, q.z, q.w)));
    float d = w + v;
    unsigned long long mask = __ballot(fkey(d) == kd);
    if (lane == 0) nidx[gi] = mask ? (unsigned)(base + __ffsll(mask) - 1) : (unsigned)base;
  } else {
    int i = (blockIdx.x - RESCAN_BLOCKS) * 256 + threadIdx.x;
    float d2 = funkey((unsigned)(m2[i] >> 32));
    float d1 = funkey(m1[i]);
    float s2 = block_sum(d2, ws);
    float s1 = block_sum(d1, ws);
    if (threadIdx.x == 0) { atomicAdd(&sums[1], s2); atomicAdd(&sums[0], s1); }
  }
}

// per-(b,d) column sums of ne^2 and ev^2 (axis-1 normalization of reference!)
__global__ __launch_bounds__(256) void edge1_kernel(const float* __restrict__ preds,
                                                    const float* __restrict__ normals,
                                                    const int* __restrict__ edges,
                                                    const unsigned* __restrict__ nidx,
                                                    float* __restrict__ sums) {
  __shared__ float ws[4];
  int b = blockIdx.y;
  int e = blockIdx.x * 256 + threadIdx.x;
  int e0 = edges[2*e], e1 = edges[2*e+1];
  const float* pb = preds   + 3*(size_t)b*N;
  const float* nb = normals + 3*(size_t)b*N;
  float vx = pb[3*e0]   - pb[3*e1];
  float vy = pb[3*e0+1] - pb[3*e1+1];
  float vz = pb[3*e0+2] - pb[3*e1+2];
  unsigned ni = nidx[b*N + e0];
  float nx = nb[3*ni], ny = nb[3*ni+1], nz = nb[3*ni+2];
  float t;
  t = block_sum(nx*nx, ws); if (threadIdx.x == 0) atomicAdd(&sums[3  + b*3 + 0], t);
  t = block_sum(ny*ny, ws); if (threadIdx.x == 0) atomicAdd(&sums[3  + b*3 + 1], t);
  t = block_sum(nz*nz, ws); if (threadIdx.x == 0) atomicAdd(&sums[3  + b*3 + 2], t);
  t = block_sum(vx*vx, ws); if (threadIdx.x == 0) atomicAdd(&sums[15 + b*3 + 0], t);
  t = block_sum(vy*vy, ws); if (threadIdx.x == 0) atomicAdd(&sums[15 + b*3 + 1], t);
  t = block_sum(vz*vz, ws); if (threadIdx.x == 0) atomicAdd(&sums[15 + b*3 + 2], t);
}

__global__ __launch_bounds__(256) void edge2_kernel(const float* __restrict__ preds,
                                                    const float* __restrict__ normals,
                                                    const int* __restrict__ edges,
                                                    const unsigned* __restrict__ nidx,
                                                    float* __restrict__ sums) {
  __shared__ float ws[4];
  int b = blockIdx.y;
  int e = blockIdx.x * 256 + threadIdx.x;
  int e0 = edges[2*e], e1 = edges[2*e+1];
  const float* pb = preds   + 3*(size_t)b*N;
  const float* nb = normals + 3*(size_t)b*N;
  float vx = pb[3*e0]   - pb[3*e1];
  float vy = pb[3*e0+1] - pb[3*e1+1];
  float vz = pb[3*e0+2] - pb[3*e1+2];
  unsigned ni = nidx[b*N + e0];
  float nx = nb[3*ni], ny = nb[3*ni+1], nz = nb[3*ni+2];
  float inn0 = 1.f / fmaxf(sqrtf(sums[3  + b*3 + 0]), 1e-12f);
  float inn1 = 1.f / fmaxf(sqrtf(sums[3  + b*3 + 1]), 1e-12f);
  float inn2 = 1.f / fmaxf(sqrtf(sums[3  + b*3 + 2]), 1e-12f);
  float inv0 = 1.f / fmaxf(sqrtf(sums[15 + b*3 + 0]), 1e-12f);
  float inv1 = 1.f / fmaxf(sqrtf(sums[15 + b*3 + 1]), 1e-12f);
  float inv2 = 1.f / fmaxf(sqrtf(sums[15 + b*3 + 2]), 1e-12f);
  float c = fabsf(nx*inn0*vx*inv0 + ny*inn1*vy*inv1 + nz*inn2*vz*inv2);
  float t = block_sum(c, ws);
  if (threadIdx.x == 0) atomicAdd(&sums[2], t);
}

__global__ void final_kernel(const float* __restrict__ sums, float* __restrict__ out) {
  if (threadIdx.x == 0 && blockIdx.x == 0) {
    float esum = 0.f;
#pragma unroll
    for (int i = 0; i < 12; ++i) esum += sums[15 + i];
    float chamfer   = (sums[0] + sums[1]) * (1.f / (float)BN);
    float edge_loss = esum * (1.f / (float)(B * E));
    float ncl       = sums[2] * (1.f / (float)(B * E));
    out[0] = 30000.f * chamfer + 240.f * edge_loss + 200000.f * ncl;
  }
}

} // namespace

extern "C" void kernel_launch(void* const* d_in, const int* in_sizes, int n_in,
                              void* d_out, int out_size, void* d_ws, size_t ws_size,
                              hipStream_t stream) {
  (void)in_sizes; (void)n_in; (void)out_size; (void)ws_size;
  const float* preds   = (const float*)d_in[0];
  const float* gts     = (const float*)d_in[1];
  const float* normals = (const float*)d_in[2];
  const int*   edges   = (const int*)d_in[3];
  char* ws = (char*)d_ws;
  // ws layout (16B aligned): A 512K | G 512K | A2 512K | G2 512K | m2 256K | m1 128K | nidx 128K | sums
  float4*             A    = (float4*)(ws);
  float4*             G    = (float4*)(ws + 0x080000);
  float4*             A2   = (float4*)(ws + 0x100000);
  float4*             G2   = (float4*)(ws + 0x180000);
  unsigned long long* m2   = (unsigned long long*)(ws + 0x200000);
  unsigned*           m1   = (unsigned*)(ws + 0x240000);
  unsigned*           nidx = (unsigned*)(ws + 0x260000);
  float*              sums = (float*)(ws + 0x280000);
  float* out = (float*)d_out;

  prep_kernel<<<dim3(BN/256), 256, 0, stream>>>(preds, gts, A, G, (float*)A2, (float*)G2,
                                                m2, m1, sums);
  // both chamfer passes in one dispatch: z = b + 4*which; 1024 blocks (3-4/CU)
  pass_fused<<<dim3(N/CHUNK, N/(256*RT), 2*B), 256, 0, stream>>>(A, G, A2, G2, m2, m1);
  // rescan (BN/4 blocks) + reduce (BN/256 blocks) merged
  post_kernel<<<dim3(RESCAN_BLOCKS + BN/256), 256, 0, stream>>>(G, A, m2, m1, nidx, sums);
  edge1_kernel<<<dim3(E/256, B), 256, 0, stream>>>(preds, normals, edges, nidx, sums);
  edge2_kernel<<<dim3(E/256, B), 256, 0, stream>>>(preds, normals, edges, nidx, sums);
  final_kernel<<<1, 64, 0, stream>>>(sums, out);
}

// Round 8
// 101.436 us; speedup vs baseline: 1.2528x; 1.2528x over previous
//
#include <hip/hip_runtime.h>

namespace {

constexpr int B = 4;
constexpr int N = 8192;          // power of two (N = 1<<13)
constexpr int E = 24576;
constexpr int BN = B * N;
constexpr int CHUNK = 128;       // staged points per block -> 1024 blocks (4/CU)
constexpr int SUB = 64;          // argmin subblock granularity (matches rescan wave)
constexpr int RT = 16;           // rows per thread (register-tiled)

typedef float f32x2 __attribute__((ext_vector_type(2)));

// Monotonic float <-> uint mapping (total order matches float compare)
__device__ __forceinline__ unsigned fkey(float f) {
  unsigned b = __float_as_uint(f);
  return b ^ ((b & 0x80000000u) ? 0xFFFFFFFFu : 0x80000000u);
}
__device__ __forceinline__ float funkey(unsigned k) {
  unsigned b = k ^ ((k & 0x80000000u) ? 0x80000000u : 0xFFFFFFFFu);
  return __uint_as_float(b);
}
// 3-input min in one instruction (T17)
__device__ __forceinline__ float min3f(float a, float b, float c) {
  float d;
  asm("v_min3_f32 %0, %1, %2, %3" : "=v"(d) : "v"(a), "v"(b), "v"(c));
  return d;
}
// packed 2xf32 fma: D.lo = a.lo*b.lo + c.lo; D.hi = a.hi*b.hi + c.hi
__device__ __forceinline__ f32x2 pk_fma(f32x2 a, f32x2 b, f32x2 c) {
  f32x2 d;
  asm("v_pk_fma_f32 %0, %1, %2, %3" : "=v"(d) : "v"(a), "v"(b), "v"(c));
  return d;
}

// sums layout (floats): [0]=s1, [1]=s2, [2]=cos sum, [3..14]=nsq[b][d], [15..26]=vsq[b][d]

// A[i] = (-2*p, |p|^2) etc; A2/G2 = pair-packed: for pair p (points 2p,2p+1):
//   float4[2p]   = (x_{2p}, x_{2p+1}, y_{2p}, y_{2p+1})
//   float4[2p+1] = (z_{2p}, z_{2p+1}, w_{2p}, w_{2p+1})
__global__ __launch_bounds__(256) void prep_kernel(const float* __restrict__ preds,
                                                   const float* __restrict__ gts,
                                                   float4* __restrict__ A,
                                                   float4* __restrict__ G,
                                                   float* __restrict__ A2f,
                                                   float* __restrict__ G2f,
                                                   unsigned long long* __restrict__ m2,
                                                   unsigned* __restrict__ m1,
                                                   float* __restrict__ sums) {
  int i = blockIdx.x * 256 + threadIdx.x;
  float px = preds[3*i], py = preds[3*i+1], pz = preds[3*i+2];
  float gx = gts[3*i],   gy = gts[3*i+1],  gz = gts[3*i+2];
  float ax = -2.f*px, ay = -2.f*py, az = -2.f*pz, aw = px*px + py*py + pz*pz;
  float bx = -2.f*gx, by = -2.f*gy, bz = -2.f*gz, bw = gx*gx + gy*gy + gz*gz;
  A[i] = make_float4(ax, ay, az, aw);
  G[i] = make_float4(bx, by, bz, bw);
  int p8 = (i >> 1) * 8, l = i & 1;
  A2f[p8 + 0 + l] = ax; A2f[p8 + 2 + l] = ay; A2f[p8 + 4 + l] = az; A2f[p8 + 6 + l] = aw;
  G2f[p8 + 0 + l] = bx; G2f[p8 + 2 + l] = by; G2f[p8 + 4 + l] = bz; G2f[p8 + 6 + l] = bw;
  m2[i] = ~0ULL;
  m1[i] = 0xFFFFFFFFu;
  if (i < 32) sums[i] = 0.f;
}

// Fused min pass: blockIdx.z = b + 4*which.
//   which=0: rows = gts, staged = preds(packed A2) -> m2 (min over m + subblock)
//   which=1: rows = preds, staged = gts(packed G2) -> m1 (min over n)
// Each thread owns RT=16 rows; per 2 staged points per row: 3 v_pk_fma_f32 + 1 v_min3.
// Packed fma chain order == rescan's scalar fmaf chain (bitwise identical).
// NOTE (R7 lesson): no launch_bounds min-wave arg, keep w[] in regs — any
// regalloc perturbation here spilled (WRITE_SIZE +33MB scratch, pass +31us).
__global__ __launch_bounds__(256) void pass_fused(const float4* __restrict__ A,
                                                  const float4* __restrict__ G,
                                                  const float4* __restrict__ A2,
                                                  const float4* __restrict__ G2,
                                                  unsigned long long* __restrict__ m2,
                                                  unsigned* __restrict__ m1) {
  __shared__ float4 sh[CHUNK];   // CHUNK float4s = CHUNK/2 packed pair-records
  const int which = blockIdx.z >> 2, b = blockIdx.z & 3;
  const float4* __restrict__ R  = which ? A  : G;
  const float4* __restrict__ S2 = which ? G2 : A2;
  const int rt = blockIdx.y, ck = blockIdx.x;
  const int tid = threadIdx.x;
  const int base = ck * CHUNK;                 // in points
  if (tid < CHUNK) sh[tid] = S2[b * N + base + tid];
  __syncthreads();
  f32x2 x2[RT], y2[RT], z2[RT];
  float w[RT], best[RT];
  int sbb[RT];
#pragma unroll
  for (int i = 0; i < RT; ++i) {
    float4 r = R[b * N + rt * (256 * RT) + i * 256 + tid];
    float xx = -0.5f * r.x, yy = -0.5f * r.y, zz = -0.5f * r.z;
    x2[i] = f32x2{xx, xx}; y2[i] = f32x2{yy, yy}; z2[i] = f32x2{zz, zz};
    w[i] = r.w; best[i] = 3.4e38f; sbb[i] = 0;
  }
  for (int sb = 0; sb < CHUNK; sb += SUB) {
    float a[RT];
#pragma unroll
    for (int i = 0; i < RT; ++i) a[i] = 3.4e38f;
    const float4* shp = &sh[sb];
#pragma unroll 4
    for (int jr = 0; jr < SUB / 2; ++jr) {     // 32 pair-records of 2 points
      float4 qa = shp[2*jr], qb = shp[2*jr + 1];
      f32x2 qx = f32x2{qa.x, qa.y}, qy = f32x2{qa.z, qa.w};
      f32x2 qz = f32x2{qb.x, qb.y}, qw = f32x2{qb.z, qb.w};
#pragma unroll
      for (int i = 0; i < RT; ++i) {
        f32x2 t = pk_fma(z2[i], qz, qw);
        t = pk_fma(y2[i], qy, t);
        t = pk_fma(x2[i], qx, t);
        a[i] = min3f(a[i], t.x, t.y);
      }
    }
#pragma unroll
    for (int i = 0; i < RT; ++i)
      if (a[i] < best[i]) { best[i] = a[i]; sbb[i] = base + sb; }  // strict <: earliest subblock wins ties
  }
#pragma unroll
  for (int i = 0; i < RT; ++i) {
    const int gi = b * N + rt * (256 * RT) + i * 256 + tid;
    float d = w[i] + best[i];
    if (which == 0) {
      atomicMin(&m2[gi], ((unsigned long long)fkey(d) << 32) | (unsigned)sbb[i]);
    } else {
      atomicMin(&m1[gi], fkey(d));
    }
  }
}

__device__ __forceinline__ float block_sum(float v, float* ws) {
#pragma unroll
  for (int o = 32; o; o >>= 1) v += __shfl_down(v, o, 64);
  __syncthreads();
  if ((threadIdx.x & 63) == 0) ws[threadIdx.x >> 6] = v;
  __syncthreads();
  return ws[0] + ws[1] + ws[2] + ws[3];
}

// Merged: blocks [0, BN/4): rescan (one wave per row, re-scan winning 64-pt
// subblock with bitwise-identical scalar fmaf chain, ballot -> first match);
// blocks [BN/4, BN/4 + BN/256): reduce m1/m2 keys into sums.
constexpr int RESCAN_BLOCKS = BN / 4;
__global__ __launch_bounds__(256) void post_kernel(const float4* __restrict__ G,
                                                   const float4* __restrict__ A,
                                                   const unsigned long long* __restrict__ m2,
                                                   const unsigned* __restrict__ m1,
                                                   unsigned* __restrict__ nidx,
                                                   float* __restrict__ sums) {
  __shared__ float ws[4];
  if (blockIdx.x < RESCAN_BLOCKS) {
    const int row  = (blockIdx.x * 256 + threadIdx.x) >> 6;   // 4 rows per block
    const int lane = threadIdx.x & 63;
    const int b = row >> 13;          // / N
    const int n = row & (N - 1);
    const int gi = b * N + n;
    unsigned long long p = m2[gi];
    const unsigned kd = (unsigned)(p >> 32);
    const int base = (int)(unsigned)p;
    float4 r = G[gi];
    const float x = -0.5f*r.x, y = -0.5f*r.y, z = -0.5f*r.z, w = r.w;
    float4 q = A[b * N + base + lane];
    float v = fmaf(x, q.x, fmaf(y, q.y, fmaf(z, q.z, q.w)));
    float d = w + v;
    unsigned long long mask = __ballot(fkey(d) == kd);
    if (lane == 0) nidx[gi] = mask ? (unsigned)(base + __ffsll(mask) - 1) : (unsigned)base;
  } else {
    int i = (blockIdx.x - RESCAN_BLOCKS) * 256 + threadIdx.x;
    float d2 = funkey((unsigned)(m2[i] >> 32));
    float d1 = funkey(m1[i]);
    float s2 = block_sum(d2, ws);
    float s1 = block_sum(d1, ws);
    if (threadIdx.x == 0) { atomicAdd(&sums[1], s2); atomicAdd(&sums[0], s1); }
  }
}

// per-(b,d) column sums of ne^2 and ev^2 (axis-1 normalization of reference!)
__global__ __launch_bounds__(256) void edge1_kernel(const float* __restrict__ preds,
                                                    const float* __restrict__ normals,
                                                    const int* __restrict__ edges,
                                                    const unsigned* __restrict__ nidx,
                                                    float* __restrict__ sums) {
  __shared__ float ws[4];
  int b = blockIdx.y;
  int e = blockIdx.x * 256 + threadIdx.x;
  int e0 = edges[2*e], e1 = edges[2*e+1];
  const float* pb = preds   + 3*(size_t)b*N;
  const float* nb = normals + 3*(size_t)b*N;
  float vx = pb[3*e0]   - pb[3*e1];
  float vy = pb[3*e0+1] - pb[3*e1+1];
  float vz = pb[3*e0+2] - pb[3*e1+2];
  unsigned ni = nidx[b*N + e0];
  float nx = nb[3*ni], ny = nb[3*ni+1], nz = nb[3*ni+2];
  float t;
  t = block_sum(nx*nx, ws); if (threadIdx.x == 0) atomicAdd(&sums[3  + b*3 + 0], t);
  t = block_sum(ny*ny, ws); if (threadIdx.x == 0) atomicAdd(&sums[3  + b*3 + 1], t);
  t = block_sum(nz*nz, ws); if (threadIdx.x == 0) atomicAdd(&sums[3  + b*3 + 2], t);
  t = block_sum(vx*vx, ws); if (threadIdx.x == 0) atomicAdd(&sums[15 + b*3 + 0], t);
  t = block_sum(vy*vy, ws); if (threadIdx.x == 0) atomicAdd(&sums[15 + b*3 + 1], t);
  t = block_sum(vz*vz, ws); if (threadIdx.x == 0) atomicAdd(&sums[15 + b*3 + 2], t);
}

__global__ __launch_bounds__(256) void edge2_kernel(const float* __restrict__ preds,
                                                    const float* __restrict__ normals,
                                                    const int* __restrict__ edges,
                                                    const unsigned* __restrict__ nidx,
                                                    float* __restrict__ sums) {
  __shared__ float ws[4];
  int b = blockIdx.y;
  int e = blockIdx.x * 256 + threadIdx.x;
  int e0 = edges[2*e], e1 = edges[2*e+1];
  const float* pb = preds   + 3*(size_t)b*N;
  const float* nb = normals + 3*(size_t)b*N;
  float vx = pb[3*e0]   - pb[3*e1];
  float vy = pb[3*e0+1] - pb[3*e1+1];
  float vz = pb[3*e0+2] - pb[3*e1+2];
  unsigned ni = nidx[b*N + e0];
  float nx = nb[3*ni], ny = nb[3*ni+1], nz = nb[3*ni+2];
  float inn0 = 1.f / fmaxf(sqrtf(sums[3  + b*3 + 0]), 1e-12f);
  float inn1 = 1.f / fmaxf(sqrtf(sums[3  + b*3 + 1]), 1e-12f);
  float inn2 = 1.f / fmaxf(sqrtf(sums[3  + b*3 + 2]), 1e-12f);
  float inv0 = 1.f / fmaxf(sqrtf(sums[15 + b*3 + 0]), 1e-12f);
  float inv1 = 1.f / fmaxf(sqrtf(sums[15 + b*3 + 1]), 1e-12f);
  float inv2 = 1.f / fmaxf(sqrtf(sums[15 + b*3 + 2]), 1e-12f);
  float c = fabsf(nx*inn0*vx*inv0 + ny*inn1*vy*inv1 + nz*inn2*vz*inv2);
  float t = block_sum(c, ws);
  if (threadIdx.x == 0) atomicAdd(&sums[2], t);
}

__global__ void final_kernel(const float* __restrict__ sums, float* __restrict__ out) {
  if (threadIdx.x == 0 && blockIdx.x == 0) {
    float esum = 0.f;
#pragma unroll
    for (int i = 0; i < 12; ++i) esum += sums[15 + i];
    float chamfer   = (sums[0] + sums[1]) * (1.f / (float)BN);
    float edge_loss = esum * (1.f / (float)(B * E));
    float ncl       = sums[2] * (1.f / (float)(B * E));
    out[0] = 30000.f * chamfer + 240.f * edge_loss + 200000.f * ncl;
  }
}

} // namespace

extern "C" void kernel_launch(void* const* d_in, const int* in_sizes, int n_in,
                              void* d_out, int out_size, void* d_ws, size_t ws_size,
                              hipStream_t stream) {
  (void)in_sizes; (void)n_in; (void)out_size; (void)ws_size;
  const float* preds   = (const float*)d_in[0];
  const float* gts     = (const float*)d_in[1];
  const float* normals = (const float*)d_in[2];
  const int*   edges   = (const int*)d_in[3];
  char* ws = (char*)d_ws;
  // ws layout (16B aligned): A 512K | G 512K | A2 512K | G2 512K | m2 256K | m1 128K | nidx 128K | sums
  float4*             A    = (float4*)(ws);
  float4*             G    = (float4*)(ws + 0x080000);
  float4*             A2   = (float4*)(ws + 0x100000);
  float4*             G2   = (float4*)(ws + 0x180000);
  unsigned long long* m2   = (unsigned long long*)(ws + 0x200000);
  unsigned*           m1   = (unsigned*)(ws + 0x240000);
  unsigned*           nidx = (unsigned*)(ws + 0x260000);
  float*              sums = (float*)(ws + 0x280000);
  float* out = (float*)d_out;

  prep_kernel<<<dim3(BN/256), 256, 0, stream>>>(preds, gts, A, G, (float*)A2, (float*)G2,
                                                m2, m1, sums);
  // both chamfer passes in one dispatch: z = b + 4*which; 1024 blocks (4/CU)
  pass_fused<<<dim3(N/CHUNK, N/(256*RT), 2*B), 256, 0, stream>>>(A, G, A2, G2, m2, m1);
  // rescan (BN/4 blocks) + reduce (BN/256 blocks) merged
  post_kernel<<<dim3(RESCAN_BLOCKS + BN/256), 256, 0, stream>>>(G, A, m2, m1, nidx, sums);
  edge1_kernel<<<dim3(E/256, B), 256, 0, stream>>>(preds, normals, edges, nidx, sums);
  edge2_kernel<<<dim3(E/256, B), 256, 0, stream>>>(preds, normals, edges, nidx, sums);
  final_kernel<<<1, 64, 0, stream>>>(sums, out);
}

// Round 9
// 99.292 us; speedup vs baseline: 1.2799x; 1.0216x over previous
//
#include <hip/hip_runtime.h>

namespace {

constexpr int B = 4;
constexpr int N = 8192;          // power of two (N = 1<<13)
constexpr int E = 24576;
constexpr int BN = B * N;
constexpr int CHUNK = 256;       // staged points per wave-unit
constexpr int SUB = 64;          // argmin subblock granularity (matches rescan wave)
constexpr int RT = 8;            // rows per thread (register-tiled)

typedef float f32x2 __attribute__((ext_vector_type(2)));

// Monotonic float <-> uint mapping (total order matches float compare)
__device__ __forceinline__ unsigned fkey(float f) {
  unsigned b = __float_as_uint(f);
  return b ^ ((b & 0x80000000u) ? 0xFFFFFFFFu : 0x80000000u);
}
__device__ __forceinline__ float funkey(unsigned k) {
  unsigned b = k ^ ((k & 0x80000000u) ? 0x80000000u : 0xFFFFFFFFu);
  return __uint_as_float(b);
}
// 3-input min in one instruction (T17)
__device__ __forceinline__ float min3f(float a, float b, float c) {
  float d;
  asm("v_min3_f32 %0, %1, %2, %3" : "=v"(d) : "v"(a), "v"(b), "v"(c));
  return d;
}
// packed 2xf32 fma with the staged (wave-uniform) operand in SGPRs:
// one scalar operand per VALU inst is architecturally allowed.
__device__ __forceinline__ f32x2 pk_fma_vsv(f32x2 a, f32x2 bs, f32x2 c) {
  f32x2 d;
  asm("v_pk_fma_f32 %0, %1, %2, %3" : "=v"(d) : "v"(a), "s"(bs), "v"(c));
  return d;
}
__device__ __forceinline__ f32x2 pk_fma_vvv(f32x2 a, f32x2 b, f32x2 c) {
  f32x2 d;
  asm("v_pk_fma_f32 %0, %1, %2, %3" : "=v"(d) : "v"(a), "v"(b), "v"(c));
  return d;
}

// sums layout (floats): [0]=s1, [1]=s2, [2]=cos sum, [3..14]=nsq[b][d], [15..26]=vsq[b][d]

// A[i] = (-2*p, |p|^2) etc; A2/G2 = pair-packed: for pair p (points 2p,2p+1):
//   float4[2p]   = (x_{2p}, x_{2p+1}, y_{2p}, y_{2p+1})
//   float4[2p+1] = (z_{2p}, z_{2p+1}, w_{2p}, w_{2p+1})
__global__ __launch_bounds__(256) void prep_kernel(const float* __restrict__ preds,
                                                   const float* __restrict__ gts,
                                                   float4* __restrict__ A,
                                                   float4* __restrict__ G,
                                                   float* __restrict__ A2f,
                                                   float* __restrict__ G2f,
                                                   unsigned long long* __restrict__ m2,
                                                   unsigned* __restrict__ m1,
                                                   float* __restrict__ sums) {
  int i = blockIdx.x * 256 + threadIdx.x;
  float px = preds[3*i], py = preds[3*i+1], pz = preds[3*i+2];
  float gx = gts[3*i],   gy = gts[3*i+1],  gz = gts[3*i+2];
  float ax = -2.f*px, ay = -2.f*py, az = -2.f*pz, aw = px*px + py*py + pz*pz;
  float bx = -2.f*gx, by = -2.f*gy, bz = -2.f*gz, bw = gx*gx + gy*gy + gz*gz;
  A[i] = make_float4(ax, ay, az, aw);
  G[i] = make_float4(bx, by, bz, bw);
  int p8 = (i >> 1) * 8, l = i & 1;
  A2f[p8 + 0 + l] = ax; A2f[p8 + 2 + l] = ay; A2f[p8 + 4 + l] = az; A2f[p8 + 6 + l] = aw;
  G2f[p8 + 0 + l] = bx; G2f[p8 + 2 + l] = by; G2f[p8 + 4 + l] = bz; G2f[p8 + 6 + l] = bw;
  m2[i] = ~0ULL;
  m1[i] = 0xFFFFFFFFu;
  if (i < 32) sums[i] = 0.f;
}

// Barrier-free, LDS-free min pass. Each WAVE owns one unit:
//   unit = (((which*4 + b)*16 + rg)*32 + ck)   (4096 units, 1024 blocks x 4 waves)
//   which=0: rows = gts, staged = preds(A2) -> m2 (min over m + subblock argmin)
//   which=1: rows = preds, staged = gts(G2) -> m1 (min over n)
// Staged records are wave-uniform -> scalar s_load path (readfirstlane'd wave id
// makes addresses provably uniform); each pk_fma uses the record as its one
// allowed SGPR operand. Packed fma chain order == rescan's scalar fmaf chain.
__global__ __launch_bounds__(256) void pass_wave(const float4* __restrict__ A,
                                                 const float4* __restrict__ G,
                                                 const float4* __restrict__ A2,
                                                 const float4* __restrict__ G2,
                                                 unsigned long long* __restrict__ m2,
                                                 unsigned* __restrict__ m1) {
  const int wid  = __builtin_amdgcn_readfirstlane((int)(threadIdx.x >> 6));
  const int lane = threadIdx.x & 63;
  const int u    = blockIdx.x * 4 + wid;
  const int ck = u & 31, rg = (u >> 5) & 15, b = (u >> 9) & 3, which = u >> 11;
  const float4* __restrict__ R  = which ? A  : G;
  const float4* __restrict__ S2 = which ? G2 : A2;
  const float4* __restrict__ Sg = S2 + b * N + ck * CHUNK;  // uniform base
  const int base = ck * CHUNK;
  f32x2 x2[RT], y2[RT], z2[RT];
  float w[RT], best[RT];
  int sbb[RT];
#pragma unroll
  for (int i = 0; i < RT; ++i) {
    float4 r = R[b * N + rg * (64 * RT) + i * 64 + lane];
    float xx = -0.5f * r.x, yy = -0.5f * r.y, zz = -0.5f * r.z;
    x2[i] = f32x2{xx, xx}; y2[i] = f32x2{yy, yy}; z2[i] = f32x2{zz, zz};
    w[i] = r.w; best[i] = 3.4e38f; sbb[i] = 0;
  }
  for (int sb = 0; sb < CHUNK; sb += SUB) {
    float a[RT];
#pragma unroll
    for (int i = 0; i < RT; ++i) a[i] = 3.4e38f;
    const float4* Sp = Sg + sb;
#pragma unroll 4
    for (int jr = 0; jr < SUB / 2; ++jr) {     // 32 pair-records of 2 points
      float4 qa = Sp[2*jr], qb = Sp[2*jr + 1]; // uniform -> s_load_dwordx8
      f32x2 qx = f32x2{qa.x, qa.y}, qy = f32x2{qa.z, qa.w};
      f32x2 qz = f32x2{qb.x, qb.y}, qw = f32x2{qb.z, qb.w};
#pragma unroll
      for (int i = 0; i < RT; ++i) {
        f32x2 t = pk_fma_vvv(z2[i], qz, qw);   // qw needs a VGPR copy anyway
        t = pk_fma_vsv(y2[i], qy, t);
        t = pk_fma_vsv(x2[i], qx, t);
        a[i] = min3f(a[i], t.x, t.y);
      }
    }
#pragma unroll
    for (int i = 0; i < RT; ++i)
      if (a[i] < best[i]) { best[i] = a[i]; sbb[i] = base + sb; }  // strict <: earliest subblock wins ties
  }
#pragma unroll
  for (int i = 0; i < RT; ++i) {
    const int gi = b * N + rg * (64 * RT) + i * 64 + lane;
    float d = w[i] + best[i];
    if (which == 0) {
      atomicMin(&m2[gi], ((unsigned long long)fkey(d) << 32) | (unsigned)sbb[i]);
    } else {
      atomicMin(&m1[gi], fkey(d));
    }
  }
}

__device__ __forceinline__ float block_sum(float v, float* ws) {
#pragma unroll
  for (int o = 32; o; o >>= 1) v += __shfl_down(v, o, 64);
  __syncthreads();
  if ((threadIdx.x & 63) == 0) ws[threadIdx.x >> 6] = v;
  __syncthreads();
  return ws[0] + ws[1] + ws[2] + ws[3];
}

// Merged: blocks [0, BN/4): rescan (one wave per row, re-scan winning 64-pt
// subblock with bitwise-identical scalar fmaf chain, ballot -> first match);
// blocks [BN/4, BN/4 + BN/256): reduce m1/m2 keys into sums.
constexpr int RESCAN_BLOCKS = BN / 4;
__global__ __launch_bounds__(256) void post_kernel(const float4* __restrict__ G,
                                                   const float4* __restrict__ A,
                                                   const unsigned long long* __restrict__ m2,
                                                   const unsigned* __restrict__ m1,
                                                   unsigned* __restrict__ nidx,
                                                   float* __restrict__ sums) {
  __shared__ float ws[4];
  if (blockIdx.x < RESCAN_BLOCKS) {
    const int row  = (blockIdx.x * 256 + threadIdx.x) >> 6;   // 4 rows per block
    const int lane = threadIdx.x & 63;
    const int b = row >> 13;          // / N
    const int n = row & (N - 1);
    const int gi = b * N + n;
    unsigned long long p = m2[gi];
    const unsigned kd = (unsigned)(p >> 32);
    const int base = (int)(unsigned)p;
    float4 r = G[gi];
    const float x = -0.5f*r.x, y = -0.5f*r.y, z = -0.5f*r.z, w = r.w;
    float4 q = A[b * N + base + lane];
    float v = fmaf(x, q.x, fmaf(y, q.y, fmaf(z, q.z, q.w)));
    float d = w + v;
    unsigned long long mask = __ballot(fkey(d) == kd);
    if (lane == 0) nidx[gi] = mask ? (unsigned)(base + __ffsll(mask) - 1) : (unsigned)base;
  } else {
    int i = (blockIdx.x - RESCAN_BLOCKS) * 256 + threadIdx.x;
    float d2 = funkey((unsigned)(m2[i] >> 32));
    float d1 = funkey(m1[i]);
    float s2 = block_sum(d2, ws);
    float s1 = block_sum(d1, ws);
    if (threadIdx.x == 0) { atomicAdd(&sums[1], s2); atomicAdd(&sums[0], s1); }
  }
}

// per-(b,d) column sums of ne^2 and ev^2 (axis-1 normalization of reference!)
__global__ __launch_bounds__(256) void edge1_kernel(const float* __restrict__ preds,
                                                    const float* __restrict__ normals,
                                                    const int* __restrict__ edges,
                                                    const unsigned* __restrict__ nidx,
                                                    float* __restrict__ sums) {
  __shared__ float ws[4];
  int b = blockIdx.y;
  int e = blockIdx.x * 256 + threadIdx.x;
  int e0 = edges[2*e], e1 = edges[2*e+1];
  const float* pb = preds   + 3*(size_t)b*N;
  const float* nb = normals + 3*(size_t)b*N;
  float vx = pb[3*e0]   - pb[3*e1];
  float vy = pb[3*e0+1] - pb[3*e1+1];
  float vz = pb[3*e0+2] - pb[3*e1+2];
  unsigned ni = nidx[b*N + e0];
  float nx = nb[3*ni], ny = nb[3*ni+1], nz = nb[3*ni+2];
  float t;
  t = block_sum(nx*nx, ws); if (threadIdx.x == 0) atomicAdd(&sums[3  + b*3 + 0], t);
  t = block_sum(ny*ny, ws); if (threadIdx.x == 0) atomicAdd(&sums[3  + b*3 + 1], t);
  t = block_sum(nz*nz, ws); if (threadIdx.x == 0) atomicAdd(&sums[3  + b*3 + 2], t);
  t = block_sum(vx*vx, ws); if (threadIdx.x == 0) atomicAdd(&sums[15 + b*3 + 0], t);
  t = block_sum(vy*vy, ws); if (threadIdx.x == 0) atomicAdd(&sums[15 + b*3 + 1], t);
  t = block_sum(vz*vz, ws); if (threadIdx.x == 0) atomicAdd(&sums[15 + b*3 + 2], t);
}

__global__ __launch_bounds__(256) void edge2_kernel(const float* __restrict__ preds,
                                                    const float* __restrict__ normals,
                                                    const int* __restrict__ edges,
                                                    const unsigned* __restrict__ nidx,
                                                    float* __restrict__ sums) {
  __shared__ float ws[4];
  int b = blockIdx.y;
  int e = blockIdx.x * 256 + threadIdx.x;
  int e0 = edges[2*e], e1 = edges[2*e+1];
  const float* pb = preds   + 3*(size_t)b*N;
  const float* nb = normals + 3*(size_t)b*N;
  float vx = pb[3*e0]   - pb[3*e1];
  float vy = pb[3*e0+1] - pb[3*e1+1];
  float vz = pb[3*e0+2] - pb[3*e1+2];
  unsigned ni = nidx[b*N + e0];
  float nx = nb[3*ni], ny = nb[3*ni+1], nz = nb[3*ni+2];
  float inn0 = 1.f / fmaxf(sqrtf(sums[3  + b*3 + 0]), 1e-12f);
  float inn1 = 1.f / fmaxf(sqrtf(sums[3  + b*3 + 1]), 1e-12f);
  float inn2 = 1.f / fmaxf(sqrtf(sums[3  + b*3 + 2]), 1e-12f);
  float inv0 = 1.f / fmaxf(sqrtf(sums[15 + b*3 + 0]), 1e-12f);
  float inv1 = 1.f / fmaxf(sqrtf(sums[15 + b*3 + 1]), 1e-12f);
  float inv2 = 1.f / fmaxf(sqrtf(sums[15 + b*3 + 2]), 1e-12f);
  float c = fabsf(nx*inn0*vx*inv0 + ny*inn1*vy*inv1 + nz*inn2*vz*inv2);
  float t = block_sum(c, ws);
  if (threadIdx.x == 0) atomicAdd(&sums[2], t);
}

__global__ void final_kernel(const float* __restrict__ sums, float* __restrict__ out) {
  if (threadIdx.x == 0 && blockIdx.x == 0) {
    float esum = 0.f;
#pragma unroll
    for (int i = 0; i < 12; ++i) esum += sums[15 + i];
    float chamfer   = (sums[0] + sums[1]) * (1.f / (float)BN);
    float edge_loss = esum * (1.f / (float)(B * E));
    float ncl       = sums[2] * (1.f / (float)(B * E));
    out[0] = 30000.f * chamfer + 240.f * edge_loss + 200000.f * ncl;
  }
}

} // namespace

extern "C" void kernel_launch(void* const* d_in, const int* in_sizes, int n_in,
                              void* d_out, int out_size, void* d_ws, size_t ws_size,
                              hipStream_t stream) {
  (void)in_sizes; (void)n_in; (void)out_size; (void)ws_size;
  const float* preds   = (const float*)d_in[0];
  const float* gts     = (const float*)d_in[1];
  const float* normals = (const float*)d_in[2];
  const int*   edges   = (const int*)d_in[3];
  char* ws = (char*)d_ws;
  // ws layout (16B aligned): A 512K | G 512K | A2 512K | G2 512K | m2 256K | m1 128K | nidx 128K | sums
  float4*             A    = (float4*)(ws);
  float4*             G    = (float4*)(ws + 0x080000);
  float4*             A2   = (float4*)(ws + 0x100000);
  float4*             G2   = (float4*)(ws + 0x180000);
  unsigned long long* m2   = (unsigned long long*)(ws + 0x200000);
  unsigned*           m1   = (unsigned*)(ws + 0x240000);
  unsigned*           nidx = (unsigned*)(ws + 0x260000);
  float*              sums = (float*)(ws + 0x280000);
  float* out = (float*)d_out;

  prep_kernel<<<dim3(BN/256), 256, 0, stream>>>(preds, gts, A, G, (float*)A2, (float*)G2,
                                                m2, m1, sums);
  // 4096 wave-units (2 passes x 4 b x 16 rowgroups x 32 chunks), 4 waves/block
  pass_wave<<<dim3(1024), 256, 0, stream>>>(A, G, A2, G2, m2, m1);
  // rescan (BN/4 blocks) + reduce (BN/256 blocks) merged
  post_kernel<<<dim3(RESCAN_BLOCKS + BN/256), 256, 0, stream>>>(G, A, m2, m1, nidx, sums);
  edge1_kernel<<<dim3(E/256, B), 256, 0, stream>>>(preds, normals, edges, nidx, sums);
  edge2_kernel<<<dim3(E/256, B), 256, 0, stream>>>(preds, normals, edges, nidx, sums);
  final_kernel<<<1, 64, 0, stream>>>(sums, out);
}

// Round 10
// 85.326 us; speedup vs baseline: 1.4894x; 1.1637x over previous
//
#include <hip/hip_runtime.h>

namespace {

constexpr int B = 4;
constexpr int N = 8192;          // power of two (N = 1<<13)
constexpr int E = 24576;
constexpr int BN = B * N;
constexpr int CHUNK = 256;       // staged points per wave-unit
constexpr int SUB = 64;          // argmin subblock granularity (matches rescan wave)
constexpr int RT = 4;            // rows per thread -> 8192 units / 2048 blocks

typedef float f32x2 __attribute__((ext_vector_type(2)));

// Monotonic float <-> uint mapping (total order matches float compare)
__device__ __forceinline__ unsigned fkey(float f) {
  unsigned b = __float_as_uint(f);
  return b ^ ((b & 0x80000000u) ? 0xFFFFFFFFu : 0x80000000u);
}
__device__ __forceinline__ float funkey(unsigned k) {
  unsigned b = k ^ ((k & 0x80000000u) ? 0x80000000u : 0xFFFFFFFFu);
  return __uint_as_float(b);
}
// 3-input min in one instruction (T17)
__device__ __forceinline__ float min3f(float a, float b, float c) {
  float d;
  asm("v_min3_f32 %0, %1, %2, %3" : "=v"(d) : "v"(a), "v"(b), "v"(c));
  return d;
}
// packed 2xf32 fma with the staged (wave-uniform) operand in SGPRs:
// one scalar operand per VALU inst is architecturally allowed.
__device__ __forceinline__ f32x2 pk_fma_vsv(f32x2 a, f32x2 bs, f32x2 c) {
  f32x2 d;
  asm("v_pk_fma_f32 %0, %1, %2, %3" : "=v"(d) : "v"(a), "s"(bs), "v"(c));
  return d;
}

// sums layout (floats): [0]=s1, [1]=s2, [2]=cos sum, [3..14]=nsq[b][d], [15..26]=vsq[b][d]

// A[i] = (-2*p, |p|^2) etc; A2/G2 = pair-packed: for pair p (points 2p,2p+1):
//   float4[2p]   = (x_{2p}, x_{2p+1}, y_{2p}, y_{2p+1})
//   float4[2p+1] = (z_{2p}, z_{2p+1}, w_{2p}, w_{2p+1})
__global__ __launch_bounds__(256) void prep_kernel(const float* __restrict__ preds,
                                                   const float* __restrict__ gts,
                                                   float4* __restrict__ A,
                                                   float4* __restrict__ G,
                                                   float* __restrict__ A2f,
                                                   float* __restrict__ G2f,
                                                   unsigned long long* __restrict__ m2,
                                                   unsigned* __restrict__ m1,
                                                   float* __restrict__ sums) {
  int i = blockIdx.x * 256 + threadIdx.x;
  float px = preds[3*i], py = preds[3*i+1], pz = preds[3*i+2];
  float gx = gts[3*i],   gy = gts[3*i+1],  gz = gts[3*i+2];
  float ax = -2.f*px, ay = -2.f*py, az = -2.f*pz, aw = px*px + py*py + pz*pz;
  float bx = -2.f*gx, by = -2.f*gy, bz = -2.f*gz, bw = gx*gx + gy*gy + gz*gz;
  A[i] = make_float4(ax, ay, az, aw);
  G[i] = make_float4(bx, by, bz, bw);
  int p8 = (i >> 1) * 8, l = i & 1;
  A2f[p8 + 0 + l] = ax; A2f[p8 + 2 + l] = ay; A2f[p8 + 4 + l] = az; A2f[p8 + 6 + l] = aw;
  G2f[p8 + 0 + l] = bx; G2f[p8 + 2 + l] = by; G2f[p8 + 4 + l] = bz; G2f[p8 + 6 + l] = bw;
  m2[i] = ~0ULL;
  m1[i] = 0xFFFFFFFFu;
  if (i < 32) sums[i] = 0.f;
}

// Barrier-free, LDS-free min pass. Each WAVE owns one unit:
//   unit u: ck = u&31 (chunk), rg = (u>>5)&31 (256-row group), b = (u>>10)&3, which = u>>12
//   which=0: rows = gts, staged = preds(A2) -> m2 (min over m + subblock argmin)
//   which=1: rows = preds, staged = gts(G2) -> m1 (min over n)
// Staged records are wave-uniform -> scalar s_load path; every pk_fma takes the
// record as its one allowed SGPR operand (only qw needs a VGPR copy).
// Packed fma chain order == rescan's scalar fmaf chain (bitwise identical).
__global__ __launch_bounds__(256) void pass_wave(const float4* __restrict__ A,
                                                 const float4* __restrict__ G,
                                                 const float4* __restrict__ A2,
                                                 const float4* __restrict__ G2,
                                                 unsigned long long* __restrict__ m2,
                                                 unsigned* __restrict__ m1) {
  const int wid  = __builtin_amdgcn_readfirstlane((int)(threadIdx.x >> 6));
  const int lane = threadIdx.x & 63;
  const int u    = blockIdx.x * 4 + wid;
  const int ck = u & 31, rg = (u >> 5) & 31, b = (u >> 10) & 3, which = u >> 12;
  const float4* __restrict__ R  = which ? A  : G;
  const float4* __restrict__ S2 = which ? G2 : A2;
  const float4* __restrict__ Sg = S2 + b * N + ck * CHUNK;  // uniform base
  const int base = ck * CHUNK;
  f32x2 x2[RT], y2[RT], z2[RT];
  float w[RT], best[RT];
  int sbb[RT];
#pragma unroll
  for (int i = 0; i < RT; ++i) {
    float4 r = R[b * N + rg * (64 * RT) + i * 64 + lane];
    float xx = -0.5f * r.x, yy = -0.5f * r.y, zz = -0.5f * r.z;
    x2[i] = f32x2{xx, xx}; y2[i] = f32x2{yy, yy}; z2[i] = f32x2{zz, zz};
    w[i] = r.w; best[i] = 3.4e38f; sbb[i] = 0;
  }
  for (int sb = 0; sb < CHUNK; sb += SUB) {
    float a[RT];
#pragma unroll
    for (int i = 0; i < RT; ++i) a[i] = 3.4e38f;
    const float4* Sp = Sg + sb;
#pragma unroll 8
    for (int jr = 0; jr < SUB / 2; ++jr) {     // 32 pair-records of 2 points
      float4 qa = Sp[2*jr], qb = Sp[2*jr + 1]; // uniform -> s_load_dwordx8
      f32x2 qx = f32x2{qa.x, qa.y}, qy = f32x2{qa.z, qa.w};
      f32x2 qz = f32x2{qb.x, qb.y}, qw = f32x2{qb.z, qb.w};
#pragma unroll
      for (int i = 0; i < RT; ++i) {
        f32x2 t = pk_fma_vsv(z2[i], qz, qw);   // qw: one v_mov_b64 per record-pair
        t = pk_fma_vsv(y2[i], qy, t);
        t = pk_fma_vsv(x2[i], qx, t);
        a[i] = min3f(a[i], t.x, t.y);
      }
    }
#pragma unroll
    for (int i = 0; i < RT; ++i)
      if (a[i] < best[i]) { best[i] = a[i]; sbb[i] = base + sb; }  // strict <: earliest subblock wins ties
  }
#pragma unroll
  for (int i = 0; i < RT; ++i) {
    const int gi = b * N + rg * (64 * RT) + i * 64 + lane;
    float d = w[i] + best[i];
    if (which == 0) {
      atomicMin(&m2[gi], ((unsigned long long)fkey(d) << 32) | (unsigned)sbb[i]);
    } else {
      atomicMin(&m1[gi], fkey(d));
    }
  }
}

__device__ __forceinline__ float block_sum(float v, float* ws) {
#pragma unroll
  for (int o = 32; o; o >>= 1) v += __shfl_down(v, o, 64);
  __syncthreads();
  if ((threadIdx.x & 63) == 0) ws[threadIdx.x >> 6] = v;
  __syncthreads();
  return ws[0] + ws[1] + ws[2] + ws[3];
}

// Merged: blocks [0, 2048): rescan — each wave re-scans 4 rows' winning 64-pt
// subblocks (bitwise-identical scalar fmaf chain, ballot -> first match).
// m2 loads for all 4 rows issued up front to pipeline dependent chains.
// blocks [2048, 2048+128): reduce m1/m2 keys into sums.
constexpr int RESCAN_BLOCKS = 2048;   // x 4 waves x 4 rows = BN rows
__global__ __launch_bounds__(256) void post_kernel(const float4* __restrict__ G,
                                                   const float4* __restrict__ A,
                                                   const unsigned long long* __restrict__ m2,
                                                   const unsigned* __restrict__ m1,
                                                   unsigned* __restrict__ nidx,
                                                   float* __restrict__ sums) {
  __shared__ float ws[4];
  if (blockIdx.x < RESCAN_BLOCKS) {
    const int wid  = threadIdx.x >> 6;
    const int lane = threadIdx.x & 63;
    const int row0 = (blockIdx.x * 4 + wid) * 4;
    unsigned long long p[4];
    float4 r[4];
#pragma unroll
    for (int j = 0; j < 4; ++j) p[j] = m2[row0 + j];   // independent loads first
#pragma unroll
    for (int j = 0; j < 4; ++j) r[j] = G[row0 + j];
#pragma unroll
    for (int j = 0; j < 4; ++j) {
      const int gi = row0 + j;
      const int b = gi >> 13;
      const unsigned kd = (unsigned)(p[j] >> 32);
      const int base = (int)(unsigned)p[j];
      const float x = -0.5f*r[j].x, y = -0.5f*r[j].y, z = -0.5f*r[j].z, w = r[j].w;
      float4 q = A[b * N + base + lane];
      float v = fmaf(x, q.x, fmaf(y, q.y, fmaf(z, q.z, q.w)));
      float d = w + v;
      unsigned long long mask = __ballot(fkey(d) == kd);
      if (lane == 0) nidx[gi] = mask ? (unsigned)(base + __ffsll(mask) - 1) : (unsigned)base;
    }
  } else {
    int i = (blockIdx.x - RESCAN_BLOCKS) * 256 + threadIdx.x;
    float d2 = funkey((unsigned)(m2[i] >> 32));
    float d1 = funkey(m1[i]);
    float s2 = block_sum(d2, ws);
    float s1 = block_sum(d1, ws);
    if (threadIdx.x == 0) { atomicAdd(&sums[1], s2); atomicAdd(&sums[0], s1); }
  }
}

// per-(b,d) column sums of ne^2 and ev^2 (axis-1 normalization of reference!)
__global__ __launch_bounds__(256) void edge1_kernel(const float* __restrict__ preds,
                                                    const float* __restrict__ normals,
                                                    const int* __restrict__ edges,
                                                    const unsigned* __restrict__ nidx,
                                                    float* __restrict__ sums) {
  __shared__ float ws[4];
  int b = blockIdx.y;
  int e = blockIdx.x * 256 + threadIdx.x;
  int e0 = edges[2*e], e1 = edges[2*e+1];
  const float* pb = preds   + 3*(size_t)b*N;
  const float* nb = normals + 3*(size_t)b*N;
  float vx = pb[3*e0]   - pb[3*e1];
  float vy = pb[3*e0+1] - pb[3*e1+1];
  float vz = pb[3*e0+2] - pb[3*e1+2];
  unsigned ni = nidx[b*N + e0];
  float nx = nb[3*ni], ny = nb[3*ni+1], nz = nb[3*ni+2];
  float t;
  t = block_sum(nx*nx, ws); if (threadIdx.x == 0) atomicAdd(&sums[3  + b*3 + 0], t);
  t = block_sum(ny*ny, ws); if (threadIdx.x == 0) atomicAdd(&sums[3  + b*3 + 1], t);
  t = block_sum(nz*nz, ws); if (threadIdx.x == 0) atomicAdd(&sums[3  + b*3 + 2], t);
  t = block_sum(vx*vx, ws); if (threadIdx.x == 0) atomicAdd(&sums[15 + b*3 + 0], t);
  t = block_sum(vy*vy, ws); if (threadIdx.x == 0) atomicAdd(&sums[15 + b*3 + 1], t);
  t = block_sum(vz*vz, ws); if (threadIdx.x == 0) atomicAdd(&sums[15 + b*3 + 2], t);
}

__global__ __launch_bounds__(256) void edge2_kernel(const float* __restrict__ preds,
                                                    const float* __restrict__ normals,
                                                    const int* __restrict__ edges,
                                                    const unsigned* __restrict__ nidx,
                                                    float* __restrict__ sums) {
  __shared__ float ws[4];
  int b = blockIdx.y;
  int e = blockIdx.x * 256 + threadIdx.x;
  int e0 = edges[2*e], e1 = edges[2*e+1];
  const float* pb = preds   + 3*(size_t)b*N;
  const float* nb = normals + 3*(size_t)b*N;
  float vx = pb[3*e0]   - pb[3*e1];
  float vy = pb[3*e0+1] - pb[3*e1+1];
  float vz = pb[3*e0+2] - pb[3*e1+2];
  unsigned ni = nidx[b*N + e0];
  float nx = nb[3*ni], ny = nb[3*ni+1], nz = nb[3*ni+2];
  float inn0 = 1.f / fmaxf(sqrtf(sums[3  + b*3 + 0]), 1e-12f);
  float inn1 = 1.f / fmaxf(sqrtf(sums[3  + b*3 + 1]), 1e-12f);
  float inn2 = 1.f / fmaxf(sqrtf(sums[3  + b*3 + 2]), 1e-12f);
  float inv0 = 1.f / fmaxf(sqrtf(sums[15 + b*3 + 0]), 1e-12f);
  float inv1 = 1.f / fmaxf(sqrtf(sums[15 + b*3 + 1]), 1e-12f);
  float inv2 = 1.f / fmaxf(sqrtf(sums[15 + b*3 + 2]), 1e-12f);
  float c = fabsf(nx*inn0*vx*inv0 + ny*inn1*vy*inv1 + nz*inn2*vz*inv2);
  float t = block_sum(c, ws);
  if (threadIdx.x == 0) atomicAdd(&sums[2], t);
}

__global__ void final_kernel(const float* __restrict__ sums, float* __restrict__ out) {
  if (threadIdx.x == 0 && blockIdx.x == 0) {
    float esum = 0.f;
#pragma unroll
    for (int i = 0; i < 12; ++i) esum += sums[15 + i];
    float chamfer   = (sums[0] + sums[1]) * (1.f / (float)BN);
    float edge_loss = esum * (1.f / (float)(B * E));
    float ncl       = sums[2] * (1.f / (float)(B * E));
    out[0] = 30000.f * chamfer + 240.f * edge_loss + 200000.f * ncl;
  }
}

} // namespace

extern "C" void kernel_launch(void* const* d_in, const int* in_sizes, int n_in,
                              void* d_out, int out_size, void* d_ws, size_t ws_size,
                              hipStream_t stream) {
  (void)in_sizes; (void)n_in; (void)out_size; (void)ws_size;
  const float* preds   = (const float*)d_in[0];
  const float* gts     = (const float*)d_in[1];
  const float* normals = (const float*)d_in[2];
  const int*   edges   = (const int*)d_in[3];
  char* ws = (char*)d_ws;
  // ws layout (16B aligned): A 512K | G 512K | A2 512K | G2 512K | m2 256K | m1 128K | nidx 128K | sums
  float4*             A    = (float4*)(ws);
  float4*             G    = (float4*)(ws + 0x080000);
  float4*             A2   = (float4*)(ws + 0x100000);
  float4*             G2   = (float4*)(ws + 0x180000);
  unsigned long long* m2   = (unsigned long long*)(ws + 0x200000);
  unsigned*           m1   = (unsigned*)(ws + 0x240000);
  unsigned*           nidx = (unsigned*)(ws + 0x260000);
  float*              sums = (float*)(ws + 0x280000);
  float* out = (float*)d_out;

  prep_kernel<<<dim3(BN/256), 256, 0, stream>>>(preds, gts, A, G, (float*)A2, (float*)G2,
                                                m2, m1, sums);
  // 8192 wave-units (2 passes x 4 b x 32 rowgroups x 32 chunks), 4 waves/block
  pass_wave<<<dim3(2048), 256, 0, stream>>>(A, G, A2, G2, m2, m1);
  // rescan (2048 blocks, 4 rows/wave) + reduce (128 blocks) merged
  post_kernel<<<dim3(RESCAN_BLOCKS + BN/256), 256, 0, stream>>>(G, A, m2, m1, nidx, sums);
  edge1_kernel<<<dim3(E/256, B), 256, 0, stream>>>(preds, normals, edges, nidx, sums);
  edge2_kernel<<<dim3(E/256, B), 256, 0, stream>>>(preds, normals, edges, nidx, sums);
  final_kernel<<<1, 64, 0, stream>>>(sums, out);
}